// Round 9
// baseline (1990.804 us; speedup 1.0000x reference)
//
#include <hip/hip_runtime.h>
#include <math.h>

#define B 64
#define D 1024
#define H 16
#define DH 64
#define T 511
#define TT 512          // T+1
#define SMEM 256
#define DFF 4096
#define NLAYER 4
#define SCALE 0.125f
#define EPS 1e-5f
#define NBLK 512

typedef unsigned long long u64;

__device__ __forceinline__ float dot4(const float4 a, const float4 b) {
    return a.x * b.x + a.y * b.y + a.z * b.z + a.w * b.w;
}
__device__ __forceinline__ float4 f4add(float4 a, float4 b) {
    return make_float4(a.x + b.x, a.y + b.y, a.z + b.z, a.w + b.w);
}

// ---------------------------------------------------------------------------
// PRODUCER side only: agent-scope stores put intermediate data at the LLC
// (bypassing the producer's non-coherent per-XCD L2). CONSUMERS use plain
// cached loads: every intermediate address is written ONCE per run, so no
// cache can hold a stale copy (L2 miss -> LLC -> correct), and re-reads hit
// L2/L3 at full bandwidth. This removes ALL agent-read traffic (round-8's
// bottleneck: ~170 MB/layer of slow LLC atomic reads, VALUBusy 9%).
// ---------------------------------------------------------------------------
__device__ __forceinline__ void stq4(float* p, float4 v) {
    __hip_atomic_store((u64*)p,     ((u64*)&v)[0], __ATOMIC_RELAXED, __HIP_MEMORY_SCOPE_AGENT);
    __hip_atomic_store((u64*)p + 1, ((u64*)&v)[1], __ATOMIC_RELAXED, __HIP_MEMORY_SCOPE_AGENT);
}
__device__ __forceinline__ void stq1(float* p, float v) {
    __hip_atomic_store((unsigned*)p, __float_as_uint(v), __ATOMIC_RELAXED, __HIP_MEMORY_SCOPE_AGENT);
}

struct MP {
    const float *tgt, *cache, *K0, *V0, *K_mem, *V_mem;
    const float *sa_W, *sa_b, *sa_oW, *sa_ob, *ca_qW, *ca_qb, *ca_oW, *ca_ob;
    const float *W1, *b1, *W2, *b2, *ln1g, *ln1b, *ln2g, *ln2b, *ln3g, *ln3b;
    // per-layer unique intermediates (write-once per run)
    float *xa, *xb, *xc, *qsa, *ctxa, *ctxb, *u, *w, *sums;
    float *Pq, *PAsa, *PAca1, *PAca2, *Pc, *Pf1, *h1, *Pf2;
    float *qkv, *Pqkv;
    unsigned *bar;
    float *out;
};

// ---------------------------------------------------------------------------
// Fence-free two-level grid barrier (16 groups x 32 -> root), relaxed polls.
// ---------------------------------------------------------------------------
__device__ void gridbar(unsigned* bar, unsigned target) {
    asm volatile("s_waitcnt vmcnt(0)" ::: "memory");
    __syncthreads();
    if (threadIdx.x == 0) {
        const unsigned par = target & 1u;
        unsigned* gen = bar;
        unsigned* cr  = bar + 32 + par * 32;
        unsigned* cg  = bar + 128 + (par * 16 + (blockIdx.x & 15)) * 32;
        if (__hip_atomic_fetch_add(cg, 1u, __ATOMIC_RELAXED,
                                   __HIP_MEMORY_SCOPE_AGENT) == 31u) {
            __hip_atomic_store(cg, 0u, __ATOMIC_RELAXED, __HIP_MEMORY_SCOPE_AGENT);
            if (__hip_atomic_fetch_add(cr, 1u, __ATOMIC_RELAXED,
                                       __HIP_MEMORY_SCOPE_AGENT) == 15u) {
                __hip_atomic_store(cr, 0u, __ATOMIC_RELAXED, __HIP_MEMORY_SCOPE_AGENT);
                __hip_atomic_fetch_add(gen, 1u, __ATOMIC_RELAXED,
                                       __HIP_MEMORY_SCOPE_AGENT);
            }
        }
        while (__hip_atomic_load(gen, __ATOMIC_RELAXED,
                                 __HIP_MEMORY_SCOPE_AGENT) < target)
            __builtin_amdgcn_s_sleep(16);
    }
    __syncthreads();
}

// ---------------------------------------------------------------------------
// GEMM tile: partial [64 b][128 o] for k in [kb, kb+nchunk*32). Thread 4b x 8o.
// All loads plain/cached; partial output via agent stores.
// ---------------------------------------------------------------------------
__device__ void dev_gemm(const float* __restrict__ A, int lda,
                         const float* __restrict__ W, int ldw,
                         float* __restrict__ Pout, int O,
                         int obase, int kb, int nchunk, float* sm)
{
    float* As = sm;             // [32][68]
    float* Ws = sm + 32 * 68;   // [32][132]
    const int tid = threadIdx.x;
    const int b0 = (tid >> 4) * 4;
    const int o0 = (tid & 15) * 8;
    float acc[4][8];
#pragma unroll
    for (int i = 0; i < 4; ++i)
#pragma unroll
        for (int j = 0; j < 8; ++j) acc[i][j] = 0.f;

    for (int c = 0; c < nchunk; ++c) {
        const int kc = kb + c * 32;
#pragma unroll
        for (int j = 0; j < 2; ++j) {
            const int f = tid + 256 * j;
            const int bb = f >> 3, k4 = f & 7;
            const float4 v = *(const float4*)(A + (size_t)bb * lda + kc + 4 * k4);
            As[(4 * k4 + 0) * 68 + bb] = v.x; As[(4 * k4 + 1) * 68 + bb] = v.y;
            As[(4 * k4 + 2) * 68 + bb] = v.z; As[(4 * k4 + 3) * 68 + bb] = v.w;
        }
#pragma unroll
        for (int j = 0; j < 4; ++j) {
            const int f = tid + 256 * j;
            const int oo = f >> 3, k4 = f & 7;
            const float4 v = *(const float4*)(W + (size_t)(obase + oo) * ldw + kc + 4 * k4);
            Ws[(4 * k4 + 0) * 132 + oo] = v.x; Ws[(4 * k4 + 1) * 132 + oo] = v.y;
            Ws[(4 * k4 + 2) * 132 + oo] = v.z; Ws[(4 * k4 + 3) * 132 + oo] = v.w;
        }
        __syncthreads();
#pragma unroll 8
        for (int k = 0; k < 32; ++k) {
            const float4 av = *(const float4*)(As + k * 68 + b0);
            const float4 w0 = *(const float4*)(Ws + k * 132 + o0);
            const float4 w1 = *(const float4*)(Ws + k * 132 + o0 + 4);
            const float a[4] = {av.x, av.y, av.z, av.w};
            const float w[8] = {w0.x, w0.y, w0.z, w0.w, w1.x, w1.y, w1.z, w1.w};
#pragma unroll
            for (int i = 0; i < 4; ++i)
#pragma unroll
                for (int j = 0; j < 8; ++j)
                    acc[i][j] = fmaf(a[i], w[j], acc[i][j]);
        }
        __syncthreads();
    }
#pragma unroll
    for (int i = 0; i < 4; ++i) {
        const float4 v0 = make_float4(acc[i][0], acc[i][1], acc[i][2], acc[i][3]);
        const float4 v1 = make_float4(acc[i][4], acc[i][5], acc[i][6], acc[i][7]);
        stq4(Pout + (size_t)(b0 + i) * O + obase + o0, v0);
        stq4(Pout + (size_t)(b0 + i) * O + obase + o0 + 4, v1);
    }
}

// ---------------------------------------------------------------------------
// finish: out[b][o] = act(bias[o] + sum_s P[s][b][o]). Plain loads.
// ---------------------------------------------------------------------------
template <int NPART, bool RELU, int O>
__device__ void dev_finish(const float* __restrict__ P,
                           const float* __restrict__ bias,
                           float* __restrict__ out)
{
    constexpr int OC = O / 4;
    const int e = blockIdx.x * 256 + threadIdx.x;
    const int oc = e % OC, b = e / OC;
    float4 v = ((const float4*)bias)[oc];
#pragma unroll
    for (int s = 0; s < NPART; ++s)
        v = f4add(v, *(const float4*)(P + (size_t)(s * 64 + b) * O + oc * 4));
    if (RELU) {
        v.x = fmaxf(v.x, 0.f); v.y = fmaxf(v.y, 0.f);
        v.z = fmaxf(v.z, 0.f); v.w = fmaxf(v.w, 0.f);
    }
    stq4(out + (size_t)b * O + oc * 4, v);
}

// ---------------------------------------------------------------------------
// u[b,h,dbase..+127] = sum_k q[b,h,k]*Wk[h*64+k][d]; q materialized (plain).
// ---------------------------------------------------------------------------
__device__ void dev_gemm_u(const float* __restrict__ q,
                           const float* __restrict__ Wk, int h, int dbase,
                           float* __restrict__ u, float* sm)
{
    float* As = sm;
    float* Ws = sm + 32 * 68;
    const int tid = threadIdx.x;
    const int b0 = (tid >> 4) * 4;
    const int o0 = (tid & 15) * 8;
    float acc[4][8];
#pragma unroll
    for (int i = 0; i < 4; ++i)
#pragma unroll
        for (int j = 0; j < 8; ++j) acc[i][j] = 0.f;

    for (int kc = 0; kc < DH; kc += 32) {
#pragma unroll
        for (int j = 0; j < 2; ++j) {
            const int f = tid + 256 * j;
            const int bb = f >> 3, k4 = f & 7;
            const float4 v = *(const float4*)(q + (size_t)bb * D + h * DH + kc + 4 * k4);
            As[(4 * k4 + 0) * 68 + bb] = v.x; As[(4 * k4 + 1) * 68 + bb] = v.y;
            As[(4 * k4 + 2) * 68 + bb] = v.z; As[(4 * k4 + 3) * 68 + bb] = v.w;
        }
#pragma unroll
        for (int j = 0; j < 4; ++j) {
            const int f = tid + 256 * j;
            const int k = f >> 5, d4 = f & 31;
            *(float4*)(Ws + k * 132 + 4 * d4) =
                *(const float4*)(Wk + (size_t)(h * DH + kc + k) * D + dbase + 4 * d4);
        }
        __syncthreads();
#pragma unroll 8
        for (int k = 0; k < 32; ++k) {
            const float4 av = *(const float4*)(As + k * 68 + b0);
            const float4 w0 = *(const float4*)(Ws + k * 132 + o0);
            const float4 w1 = *(const float4*)(Ws + k * 132 + o0 + 4);
            const float a[4] = {av.x, av.y, av.z, av.w};
            const float w[8] = {w0.x, w0.y, w0.z, w0.w, w1.x, w1.y, w1.z, w1.w};
#pragma unroll
            for (int i = 0; i < 4; ++i)
#pragma unroll
                for (int j = 0; j < 8; ++j)
                    acc[i][j] = fmaf(a[i], w[j], acc[i][j]);
        }
        __syncthreads();
    }
#pragma unroll
    for (int i = 0; i < 4; ++i) {
        const float4 v0 = make_float4(acc[i][0], acc[i][1], acc[i][2], acc[i][3]);
        const float4 v1 = make_float4(acc[i][4], acc[i][5], acc[i][6], acc[i][7]);
        float* ur = u + ((size_t)(b0 + i) * H + h) * D + dbase + o0;
        stq4(ur, v0);
        stq4(ur + 4, v1);
    }
}

// ---------------------------------------------------------------------------
// Streaming self-attn: block (b, hp) owns heads 2hp,2hp+1 for ALL 512 tokens.
// Rows read straight from global (L3 serves the 8x hp re-read; HBM once).
// 4 waves stride tokens; 32-lane halves = 2 heads; final LDS cross-wave
// reduction writes FINAL w[b,h,:] and sumE (no partial buffers at all).
// ---------------------------------------------------------------------------
__device__ void dev_sattn(const float* __restrict__ cache_i, const float* __restrict__ xin,
                          const float* __restrict__ u, int b, int hp,
                          float* __restrict__ wout, float* __restrict__ sums, float* sm)
{
    const int tid = threadIdx.x;
    const int wv = tid >> 6;            // wave 0..3 (token stride)
    const int half = (tid >> 5) & 1;    // head within pair
    const int seg = tid & 31;
    const int h = hp * 2 + half;
    const int dof = seg * 4;

    float4 ur[8], ar[8];
    const float* ub = u + ((size_t)(b * H + h)) * D;
#pragma unroll
    for (int c = 0; c < 8; ++c) {
        const float4 v = *(const float4*)(ub + c * 128 + dof);
        ur[c] = make_float4(v.x * SCALE, v.y * SCALE, v.z * SCALE, v.w * SCALE);
        ar[c] = make_float4(0.f, 0.f, 0.f, 0.f);
    }
    float sumE = 0.f;

    const float* xrow = xin + (size_t)b * D;
    for (int k = 0; k < 128; ++k) {
        const int t = 4 * k + wv;
        const float* row = (t < T) ? (cache_i + ((size_t)t * B + b) * D) : xrow;
        float4 rv[8];
        float dot = 0.f;
#pragma unroll
        for (int c = 0; c < 8; ++c) {
            rv[c] = *(const float4*)(row + c * 128 + dof);
            dot += dot4(ur[c], rv[c]);
        }
#pragma unroll
        for (int m = 16; m >= 1; m >>= 1) dot += __shfl_xor(dot, m, 64);
        const float e = __expf(dot);
        sumE += e;
#pragma unroll
        for (int c = 0; c < 8; ++c) {
            ar[c].x = fmaf(e, rv[c].x, ar[c].x);
            ar[c].y = fmaf(e, rv[c].y, ar[c].y);
            ar[c].z = fmaf(e, rv[c].z, ar[c].z);
            ar[c].w = fmaf(e, rv[c].w, ar[c].w);
        }
    }

    // cross-wave reduction: red[wv][half][1024] + sumE slots
    float* red = sm;
    __syncthreads();
#pragma unroll
    for (int c = 0; c < 8; ++c)
        *(float4*)(red + (wv * 2 + half) * 1024 + c * 128 + dof) = ar[c];
    if (seg == 0) red[8192 + wv * 2 + half] = sumE;
    __syncthreads();

    const int half2 = tid >> 7;          // output head
    const int idx = (tid & 127) * 8;     // 8 floats per thread
    float4 v0 = make_float4(0.f, 0.f, 0.f, 0.f);
    float4 v1 = make_float4(0.f, 0.f, 0.f, 0.f);
#pragma unroll
    for (int ww = 0; ww < 4; ++ww) {
        v0 = f4add(v0, *(const float4*)(red + (ww * 2 + half2) * 1024 + idx));
        v1 = f4add(v1, *(const float4*)(red + (ww * 2 + half2) * 1024 + idx + 4));
    }
    float* wp = wout + ((size_t)(b * H + hp * 2 + half2)) * D + idx;
    stq4(wp, v0);
    stq4(wp + 4, v1);
    if (tid < 2) {
        const float s = red[8192 + tid] + red[8194 + tid] +
                        red[8196 + tid] + red[8198 + tid];
        stq1(sums + b * H + hp * 2 + tid, s);
    }
}

// ---------------------------------------------------------------------------
// ctx partial (k-slice of 128): A = w[b,h,:]*(1/sumE), plain loads.
// 128 blocks: (h, ks of 8). Output Pc[ks] (8 partials).
// ---------------------------------------------------------------------------
__device__ void dev_gemm_ctx(const float* __restrict__ w, const float* __restrict__ sums,
                             const float* __restrict__ Wv, int h, int ks,
                             float* __restrict__ Pout, float* sm)
{
    float* As = sm;
    float* Ws = sm + 32 * 68;
    float* sinv = sm + 6400;
    const int tid = threadIdx.x;
    if (tid < 64) sinv[tid] = 1.f / sums[tid * H + h];
    __syncthreads();

    const int b0 = (tid >> 4) * 4;
    const int o0 = (tid & 15) * 4;
    float acc[4][4];
#pragma unroll
    for (int i = 0; i < 4; ++i)
#pragma unroll
        for (int j = 0; j < 4; ++j) acc[i][j] = 0.f;

    const int kb = ks * 128;
    for (int kc = 0; kc < 128; kc += 32) {
#pragma unroll
        for (int j = 0; j < 2; ++j) {
            const int f = tid + 256 * j;
            const int bb = f >> 3, k4 = f & 7;
            const int kg = kb + kc + 4 * k4;
            const float4 v = *(const float4*)(w + ((size_t)(bb * H + h)) * D + kg);
            const float iv = sinv[bb];
            As[(4 * k4 + 0) * 68 + bb] = v.x * iv; As[(4 * k4 + 1) * 68 + bb] = v.y * iv;
            As[(4 * k4 + 2) * 68 + bb] = v.z * iv; As[(4 * k4 + 3) * 68 + bb] = v.w * iv;
        }
#pragma unroll
        for (int j = 0; j < 2; ++j) {
            const int f = tid + 256 * j;
            const int oo = f >> 3, k4 = f & 7;
            const float4 v = *(const float4*)(Wv + (size_t)(h * DH + oo) * D + kb + kc + 4 * k4);
            Ws[(4 * k4 + 0) * 68 + oo] = v.x; Ws[(4 * k4 + 1) * 68 + oo] = v.y;
            Ws[(4 * k4 + 2) * 68 + oo] = v.z; Ws[(4 * k4 + 3) * 68 + oo] = v.w;
        }
        __syncthreads();
#pragma unroll 8
        for (int k = 0; k < 32; ++k) {
            const float4 av = *(const float4*)(As + k * 68 + b0);
            const float4 wv = *(const float4*)(Ws + k * 68 + o0);
            const float a[4] = {av.x, av.y, av.z, av.w};
            const float ww[4] = {wv.x, wv.y, wv.z, wv.w};
#pragma unroll
            for (int i = 0; i < 4; ++i)
#pragma unroll
                for (int j = 0; j < 4; ++j)
                    acc[i][j] = fmaf(a[i], ww[j], acc[i][j]);
        }
        __syncthreads();
    }
#pragma unroll
    for (int i = 0; i < 4; ++i) {
        const float4 v = make_float4(acc[i][0], acc[i][1], acc[i][2], acc[i][3]);
        stq4(Pout + (size_t)(b0 + i) * D + h * DH + o0, v);
    }
}

// ---------------------------------------------------------------------------
// finish + residual + LayerNorm for row b (plain loads).
// ---------------------------------------------------------------------------
template <int NPART>
__device__ void dev_ln(const float* __restrict__ Pp,
                       const float* __restrict__ bias, const float* __restrict__ resid,
                       const float* __restrict__ gg, const float* __restrict__ bbv,
                       float* __restrict__ out, int b, float* sm)
{
    float* red = sm;
    float* red2 = sm + 8;
    const int tid = threadIdx.x;
    float4 v = ((const float4*)bias)[tid];
    v = f4add(v, *(const float4*)(resid + (size_t)b * D + tid * 4));
#pragma unroll
    for (int s = 0; s < NPART; ++s)
        v = f4add(v, *(const float4*)(Pp + (size_t)(s * 64 + b) * D + tid * 4));

    float ssum = v.x + v.y + v.z + v.w;
#pragma unroll
    for (int m = 32; m >= 1; m >>= 1) ssum += __shfl_xor(ssum, m, 64);
    if ((tid & 63) == 0) red[tid >> 6] = ssum;
    __syncthreads();
    const float mean = (red[0] + red[1] + red[2] + red[3]) * (1.f / D);
    const float dx = v.x - mean, dy = v.y - mean, dz = v.z - mean, dw = v.w - mean;
    float q = dx * dx + dy * dy + dz * dz + dw * dw;
#pragma unroll
    for (int m = 32; m >= 1; m >>= 1) q += __shfl_xor(q, m, 64);
    if ((tid & 63) == 0) red2[tid >> 6] = q;
    __syncthreads();
    const float var = (red2[0] + red2[1] + red2[2] + red2[3]) * (1.f / D);
    const float rs = rsqrtf(var + EPS);
    const float4 gv = ((const float4*)gg)[tid];
    const float4 bv = ((const float4*)bbv)[tid];
    float4 o;
    o.x = dx * rs * gv.x + bv.x;
    o.y = dy * rs * gv.y + bv.y;
    o.z = dz * rs * gv.z + bv.z;
    o.w = dw * rs * gv.w + bv.w;
    stq4(out + (size_t)b * D + tid * 4, o);
}

// ---------------------------------------------------------------------------
// Fused attention for one (b,h). HASX (L0): q/k/v from materialized qkv.
// Else: q from 16 PA partials + bias. All plain loads; ctx via agent store.
// ---------------------------------------------------------------------------
template <int NS, bool HASX>
__device__ void dev_attn(const float* __restrict__ qsrc, const float* __restrict__ qbias,
                         int b, int h,
                         const float* __restrict__ Kb, const float* __restrict__ Vb,
                         int nk, float* __restrict__ ctx, float* sm)
{
    float* qs = sm;
    float* kx = sm + 64;
    float* vx = sm + 128;
    float* r1 = sm + 192;
    float* r2 = sm + 200;
    float* sa = sm + 256;          // NS
    float* red = sm + 768;
    const int tid = threadIdx.x;
    __syncthreads();   // protect sm reuse across consecutive calls

    if (HASX) {
        if (tid < 64) {
            const float* base = qsrc + (size_t)b * 3 * D + h * DH + tid;
            qs[tid] = base[0];
            kx[tid] = base[D];
            vx[tid] = base[2 * D];
        }
        __syncthreads();
    } else {
        const int grp = tid >> 6, col = tid & 63;
        float a = 0.f;
#pragma unroll
        for (int s = 0; s < 4; ++s)
            a += qsrc[(size_t)((grp * 4 + s) * 64 + b) * D + h * DH + col];
        red[grp * 64 + col] = a;
        __syncthreads();
        if (tid < 64)
            qs[tid] = qbias[h * DH + tid] + red[tid] + red[64 + tid] +
                      red[128 + tid] + red[192 + tid];
        __syncthreads();
    }

    const int ss = tid >> 2, pp = tid & 3;
    const float* Kbh = Kb + ((size_t)(b * H + h)) * nk * DH;
#pragma unroll 2
    for (int pass = 0; pass < NS / 64; ++pass) {
        const int s = pass * 64 + ss;
        const float* row = (!HASX || s < nk) ? (Kbh + (size_t)s * DH) : kx;
        const float4* rp = (const float4*)row;
        const float4* qp = (const float4*)qs;
        float acc = 0.f;
#pragma unroll
        for (int c = 0; c < 4; ++c) acc += dot4(rp[pp * 4 + c], qp[pp * 4 + c]);
        acc += __shfl_xor(acc, 1, 64);
        acc += __shfl_xor(acc, 2, 64);
        if (pp == 0) sa[s] = acc * SCALE;
    }
    __syncthreads();

    float m = -1e30f;
    for (int k = tid; k < NS; k += 256) m = fmaxf(m, sa[k]);
#pragma unroll
    for (int mm = 32; mm >= 1; mm >>= 1) m = fmaxf(m, __shfl_xor(m, mm, 64));
    if ((tid & 63) == 0) r1[tid >> 6] = m;
    __syncthreads();
    m = fmaxf(fmaxf(r1[0], r1[1]), fmaxf(r1[2], r1[3]));
    float sum = 0.f;
    for (int k = tid; k < NS; k += 256) {
        const float e = __expf(sa[k] - m);
        sa[k] = e;
        sum += e;
    }
#pragma unroll
    for (int mm = 32; mm >= 1; mm >>= 1) sum += __shfl_xor(sum, mm, 64);
    if ((tid & 63) == 0) r2[tid >> 6] = sum;
    __syncthreads();
    const float inv = 1.f / (r2[0] + r2[1] + r2[2] + r2[3]);

    const int dh4 = tid & 15, sq = tid >> 4;
    const float* Vbh = Vb + ((size_t)(b * H + h)) * nk * DH;
    float4 acc = make_float4(0.f, 0.f, 0.f, 0.f);
#pragma unroll 2
    for (int s = sq; s < NS; s += 16) {
        const float* row = (!HASX || s < nk) ? (Vbh + (size_t)s * DH) : vx;
        const float4 vv = *(const float4*)(row + dh4 * 4);
        const float aw = sa[s];
        acc.x += aw * vv.x; acc.y += aw * vv.y;
        acc.z += aw * vv.z; acc.w += aw * vv.w;
    }
    __syncthreads();
    *(float4*)(red + sq * 68 + dh4 * 4) = acc;
    __syncthreads();
    if (tid < 64) {
        float t = 0.f;
#pragma unroll
        for (int k = 0; k < 16; ++k) t += red[k * 68 + tid];
        stq1(ctx + (size_t)b * D + h * DH + tid, t * inv);
    }
}

// ---------------------------------------------------------------------------
__global__ __launch_bounds__(256, 2) void mega(MP p)
{
    __shared__ float sm[8200];
    const int bid = blockIdx.x;
    unsigned bt = 0;
#define GB() do { ++bt; gridbar(p.bar, bt); } while (0)
    // per-layer buffer strides (floats)
    const size_t S_X = 65536, S_U = 1048576, S_W = 1048576;
    const size_t S_PQ = 1048576, S_PA = 1048576, S_PC = 524288;
    const size_t S_PF1 = 2097152, S_H1 = 262144, S_PF2 = 2097152;

    for (int L = 0; L < NLAYER; ++L) {
        const float* Wqkv = p.sa_W + (size_t)L * 3 * D * D;
        const float* bqkv = p.sa_b + (size_t)L * 3 * D;
        const float* xin = (L == 0) ? p.tgt : p.xc + (size_t)(L - 1) * S_X;
        float* xa = p.xa + (size_t)L * S_X;
        float* xb = p.xb + (size_t)L * S_X;
        float* xc = p.xc + (size_t)L * S_X;
        float* ctxa = p.ctxa + (size_t)L * S_X;
        float* ctxb = p.ctxb + (size_t)L * S_X;

        if (L == 0) {
            if (bid < 384) {
                const int og = bid % 24, ks = bid / 24;
                dev_gemm(p.tgt, D, Wqkv, D, p.Pqkv + (size_t)ks * B * 3 * D,
                         3 * D, og * 128, ks * 64, 2, sm);
            }
            GB();
            if (bid < 192) dev_finish<16, false, 3 * D>(p.Pqkv, bqkv, p.qkv);
            GB();
#pragma unroll 1
            for (int j = 0; j < 2; ++j) {
                const int pair = bid * 2 + j;
                dev_attn<TT, true>(p.qkv, nullptr, pair >> 4, pair & 15,
                                   p.K0, p.V0, T, ctxa, sm);
            }
            GB();
        } else {
            const float* cache_i = p.cache + (size_t)L * T * B * D;
            float* Pq = p.Pq + (size_t)L * S_PQ;
            float* qsa = p.qsa + (size_t)L * S_X;
            float* uL = p.u + (size_t)L * S_U;
            float* wL = p.w + (size_t)L * S_W;
            float* sumsL = p.sums + (size_t)L * 1024;
            float* Pc = p.Pc + (size_t)L * S_PC;

            if (bid < 128) {
                const int og = bid & 7, ks = bid >> 3;
                dev_gemm(xin, D, Wqkv, D, Pq + (size_t)ks * B * D, D,
                         og * 128, ks * 64, 2, sm);
            }
            GB();
            if (bid < 64) dev_finish<16, false, D>(Pq, bqkv, qsa);
            GB();
            if (bid < 128)
                dev_gemm_u(qsa, Wqkv + (size_t)D * D, bid >> 3, (bid & 7) * 128,
                           uL, sm);
            GB();
            dev_sattn(cache_i, xin, uL, bid >> 3, bid & 7, wL, sumsL, sm);
            GB();
            if (bid < 128)
                dev_gemm_ctx(wL, sumsL, Wqkv + (size_t)2 * D * D, bid >> 3,
                             bid & 7, Pc + (size_t)(bid & 7) * B * D, sm);
            GB();
            if (bid < 64) dev_finish<8, false, D>(Pc, bqkv + 2 * D, ctxa);
            GB();
        }

        // self-attn output projection + LN1
        {
            float* PAsa = p.PAsa + (size_t)L * S_PA;
            if (bid < 128) {
                const int og = bid & 7, ks = bid >> 3;
                dev_gemm(ctxa, D, p.sa_oW + (size_t)L * D * D, D,
                         PAsa + (size_t)ks * B * D, D, og * 128, ks * 64, 2, sm);
            }
            GB();
            if (bid < B)
                dev_ln<16>(PAsa, p.sa_ob + (size_t)L * D, xin,
                           p.ln1g + (size_t)L * D, p.ln1b + (size_t)L * D, xa, bid, sm);
            GB();
        }

        // cross attention
        {
            float* PAca1 = p.PAca1 + (size_t)L * S_PA;
            float* PAca2 = p.PAca2 + (size_t)L * S_PA;
            if (bid < 128) {
                const int og = bid & 7, ks = bid >> 3;
                dev_gemm(xa, D, p.ca_qW + (size_t)L * D * D, D,
                         PAca1 + (size_t)ks * B * D, D, og * 128, ks * 64, 2, sm);
            }
            GB();
            const float* Kc = p.K_mem + (size_t)L * B * H * SMEM * DH;
            const float* Vc = p.V_mem + (size_t)L * B * H * SMEM * DH;
#pragma unroll 1
            for (int j = 0; j < 2; ++j) {
                const int pair = bid * 2 + j;
                dev_attn<SMEM, false>(PAca1, p.ca_qb + (size_t)L * D,
                                      pair >> 4, pair & 15, Kc, Vc, SMEM, ctxb, sm);
            }
            GB();
            if (bid < 128) {
                const int og = bid & 7, ks = bid >> 3;
                dev_gemm(ctxb, D, p.ca_oW + (size_t)L * D * D, D,
                         PAca2 + (size_t)ks * B * D, D, og * 128, ks * 64, 2, sm);
            }
            GB();
            if (bid < B)
                dev_ln<16>(PAca2, p.ca_ob + (size_t)L * D, xa,
                           p.ln2g + (size_t)L * D, p.ln2b + (size_t)L * D, xb, bid, sm);
            GB();
        }

        // FFN
        {
            float* Pf1 = p.Pf1 + (size_t)L * S_PF1;
            float* h1 = p.h1 + (size_t)L * S_H1;
            float* Pf2 = p.Pf2 + (size_t)L * S_PF2;
            if (bid < 256) {
                const int og = bid & 31, ks = bid >> 5;   // 32 og x 8 ks
                dev_gemm(xb, D, p.W1 + (size_t)L * DFF * D, D,
                         Pf1 + (size_t)ks * B * DFF, DFF, og * 128, ks * 128, 4, sm);
            }
            GB();
            if (bid < 256) dev_finish<8, true, DFF>(Pf1, p.b1 + (size_t)L * DFF, h1);
            GB();
            if (bid < 256) {
                const int og = bid & 7, ks = bid >> 3;    // 8 og x 32 ks
                dev_gemm(h1, DFF, p.W2 + (size_t)L * D * DFF, DFF,
                         Pf2 + (size_t)ks * B * D, D, og * 128, ks * 128, 4, sm);
            }
            GB();
            float* lnout = (L == NLAYER - 1) ? p.out : xc;
            if (bid < B)
                dev_ln<32>(Pf2, p.b2 + (size_t)L * D, xb,
                           p.ln3g + (size_t)L * D, p.ln3b + (size_t)L * D,
                           lnout, bid, sm);
            GB();
        }
    }
#undef GB
}

// ---------------------------------------------------------------------------
extern "C" void kernel_launch(void* const* d_in, const int* in_sizes, int n_in,
                              void* d_out, int out_size, void* d_ws, size_t ws_size,
                              hipStream_t stream)
{
    hipMemsetAsync(d_ws, 0, 16384, stream);   // zero barrier counters

    float* ws = (float*)d_ws;
    MP p;
    p.tgt   = (const float*)d_in[0];
    p.cache = (const float*)d_in[1];
    p.K0    = (const float*)d_in[2];
    p.V0    = (const float*)d_in[3];
    p.K_mem = (const float*)d_in[4];
    p.V_mem = (const float*)d_in[5];
    p.sa_W  = (const float*)d_in[6];
    p.sa_b  = (const float*)d_in[7];
    p.sa_oW = (const float*)d_in[8];
    p.sa_ob = (const float*)d_in[9];
    p.ca_qW = (const float*)d_in[10];
    p.ca_qb = (const float*)d_in[11];
    p.ca_oW = (const float*)d_in[12];
    p.ca_ob = (const float*)d_in[13];
    p.W1    = (const float*)d_in[14];
    p.b1    = (const float*)d_in[15];
    p.W2    = (const float*)d_in[16];
    p.b2    = (const float*)d_in[17];
    p.ln1g  = (const float*)d_in[18];
    p.ln1b  = (const float*)d_in[19];
    p.ln2g  = (const float*)d_in[20];
    p.ln2b  = (const float*)d_in[21];
    p.ln3g  = (const float*)d_in[22];
    p.ln3b  = (const float*)d_in[23];

    p.bar = (unsigned*)d_ws;                 // 16 KB
    float* c = ws + 4096;
    // per-layer unique (write-once) buffers; strides match kernel constants
    p.xa    = c; c += 4 * 65536;
    p.xb    = c; c += 4 * 65536;
    p.xc    = c; c += 4 * 65536;
    p.qsa   = c; c += 4 * 65536;
    p.ctxa  = c; c += 4 * 65536;
    p.ctxb  = c; c += 4 * 65536;
    p.u     = c; c += 4 * 1048576;
    p.w     = c; c += 4 * 1048576;
    p.sums  = c; c += 4 * 1024;
    p.Pq    = c; c += 4 * 1048576;
    p.PAsa  = c; c += 4 * 1048576;
    p.PAca1 = c; c += 4 * 1048576;
    p.PAca2 = c; c += 4 * 1048576;
    p.Pc    = c; c += 4 * 524288;
    p.Pf1   = c; c += 4 * 2097152;
    p.h1    = c; c += 4 * 262144;
    p.Pf2   = c; c += 4 * 2097152;
    p.qkv   = c; c += 196608;
    p.Pqkv  = c; c += 16 * B * 3 * D;
    p.out   = (float*)d_out;

    mega<<<dim3(NBLK), dim3(256), 0, stream>>>(p);
}

// Round 10
// 805.236 us; speedup vs baseline: 2.4723x; 2.4723x over previous
//
#include <hip/hip_runtime.h>
#include <math.h>

#define B 64
#define D 1024
#define H 16
#define DH 64
#define T 511
#define TT 512          // T+1
#define SMEM 256
#define DFF 4096
#define NLAYER 4
#define SCALE 0.125f
#define EPS 1e-5f

__device__ __forceinline__ float dot4(const float4 a, const float4 b) {
    return a.x * b.x + a.y * b.y + a.z * b.z + a.w * b.w;
}
__device__ __forceinline__ float4 f4add(float4 a, float4 b) {
    return make_float4(a.x + b.x, a.y + b.y, a.z + b.z, a.w + b.w);
}

// ---------------------------------------------------------------------------
// Batch-shared GEMM: P[ks][64][O] = A[64][K-slice] @ W[O][K-slice]^T
// grid (O/128, KS), block 256. Thread tile 4b x 8o.
// ---------------------------------------------------------------------------
template <int K, int KS>
__global__ __launch_bounds__(256) void gemm_proj(
    const float* __restrict__ A, const float* __restrict__ W,
    float* __restrict__ P)
{
    constexpr int KSUB = K / KS;
    const int O = gridDim.x * 128;
    const int obase = blockIdx.x * 128;
    const int kb = blockIdx.y * KSUB;
    const int tid = threadIdx.x;

    __shared__ float As[32][68];
    __shared__ float Ws[32][132];

    const int b0 = (tid >> 4) * 4;
    const int o0 = (tid & 15) * 8;

    float acc[4][8];
#pragma unroll
    for (int i = 0; i < 4; ++i)
#pragma unroll
        for (int j = 0; j < 8; ++j) acc[i][j] = 0.f;

    for (int kc = 0; kc < KSUB; kc += 32) {
#pragma unroll
        for (int j = 0; j < 2; ++j) {
            const int f = tid + 256 * j;
            const int bb = f >> 3, k4 = f & 7;
            const float4 v = *reinterpret_cast<const float4*>(
                A + (size_t)bb * K + kb + kc + 4 * k4);
            As[4 * k4 + 0][bb] = v.x; As[4 * k4 + 1][bb] = v.y;
            As[4 * k4 + 2][bb] = v.z; As[4 * k4 + 3][bb] = v.w;
        }
#pragma unroll
        for (int j = 0; j < 4; ++j) {
            const int f = tid + 256 * j;
            const int oo = f >> 3, k4 = f & 7;
            const float4 v = *reinterpret_cast<const float4*>(
                W + (size_t)(obase + oo) * K + kb + kc + 4 * k4);
            Ws[4 * k4 + 0][oo] = v.x; Ws[4 * k4 + 1][oo] = v.y;
            Ws[4 * k4 + 2][oo] = v.z; Ws[4 * k4 + 3][oo] = v.w;
        }
        __syncthreads();
#pragma unroll 8
        for (int k = 0; k < 32; ++k) {
            const float4 av = *reinterpret_cast<const float4*>(&As[k][b0]);
            const float4 w0 = *reinterpret_cast<const float4*>(&Ws[k][o0]);
            const float4 w1 = *reinterpret_cast<const float4*>(&Ws[k][o0 + 4]);
            const float a[4] = {av.x, av.y, av.z, av.w};
            const float w[8] = {w0.x, w0.y, w0.z, w0.w, w1.x, w1.y, w1.z, w1.w};
#pragma unroll
            for (int i = 0; i < 4; ++i)
#pragma unroll
                for (int j = 0; j < 8; ++j)
                    acc[i][j] = fmaf(a[i], w[j], acc[i][j]);
        }
        __syncthreads();
    }

    float* Pb = P + (size_t)blockIdx.y * 64 * O;
#pragma unroll
    for (int i = 0; i < 4; ++i) {
        const float4 v0 = make_float4(acc[i][0], acc[i][1], acc[i][2], acc[i][3]);
        const float4 v1 = make_float4(acc[i][4], acc[i][5], acc[i][6], acc[i][7]);
        *reinterpret_cast<float4*>(Pb + (size_t)(b0 + i) * O + obase + o0) = v0;
        *reinterpret_cast<float4*>(Pb + (size_t)(b0 + i) * O + obase + o0 + 4) = v1;
    }
}

// ---------------------------------------------------------------------------
// GEMM with A = act(abias + sum of NPART partials). Cached loads.
// ---------------------------------------------------------------------------
template <int K, int KS, int NPART, bool RELU_A>
__global__ __launch_bounds__(256) void gemm_psum(
    const float* __restrict__ Pa, const float* __restrict__ abias,
    const float* __restrict__ W, float* __restrict__ P)
{
    constexpr int KSUB = K / KS;
    const int O = gridDim.x * 128;
    const int obase = blockIdx.x * 128;
    const int kb = blockIdx.y * KSUB;
    const int tid = threadIdx.x;

    __shared__ float As[32][68];
    __shared__ float Ws[32][132];

    const int b0 = (tid >> 4) * 4;
    const int o0 = (tid & 15) * 8;

    float acc[4][8];
#pragma unroll
    for (int i = 0; i < 4; ++i)
#pragma unroll
        for (int j = 0; j < 8; ++j) acc[i][j] = 0.f;

    for (int kc = 0; kc < KSUB; kc += 32) {
#pragma unroll
        for (int j = 0; j < 2; ++j) {
            const int f = tid + 256 * j;
            const int bb = f >> 3, k4 = f & 7;
            const int kg = kb + kc + 4 * k4;
            float4 v = *reinterpret_cast<const float4*>(abias + kg);
#pragma unroll
            for (int s = 0; s < NPART; ++s)
                v = f4add(v, *reinterpret_cast<const float4*>(
                    Pa + (size_t)(s * 64 + bb) * K + kg));
            if (RELU_A) {
                v.x = fmaxf(v.x, 0.f); v.y = fmaxf(v.y, 0.f);
                v.z = fmaxf(v.z, 0.f); v.w = fmaxf(v.w, 0.f);
            }
            As[4 * k4 + 0][bb] = v.x; As[4 * k4 + 1][bb] = v.y;
            As[4 * k4 + 2][bb] = v.z; As[4 * k4 + 3][bb] = v.w;
        }
#pragma unroll
        for (int j = 0; j < 4; ++j) {
            const int f = tid + 256 * j;
            const int oo = f >> 3, k4 = f & 7;
            const float4 v = *reinterpret_cast<const float4*>(
                W + (size_t)(obase + oo) * K + kb + kc + 4 * k4);
            Ws[4 * k4 + 0][oo] = v.x; Ws[4 * k4 + 1][oo] = v.y;
            Ws[4 * k4 + 2][oo] = v.z; Ws[4 * k4 + 3][oo] = v.w;
        }
        __syncthreads();
#pragma unroll 8
        for (int k = 0; k < 32; ++k) {
            const float4 av = *reinterpret_cast<const float4*>(&As[k][b0]);
            const float4 w0 = *reinterpret_cast<const float4*>(&Ws[k][o0]);
            const float4 w1 = *reinterpret_cast<const float4*>(&Ws[k][o0 + 4]);
            const float a[4] = {av.x, av.y, av.z, av.w};
            const float w[8] = {w0.x, w0.y, w0.z, w0.w, w1.x, w1.y, w1.z, w1.w};
#pragma unroll
            for (int i = 0; i < 4; ++i)
#pragma unroll
                for (int j = 0; j < 8; ++j)
                    acc[i][j] = fmaf(a[i], w[j], acc[i][j]);
        }
        __syncthreads();
    }

    float* Pb = P + (size_t)blockIdx.y * 64 * O;
#pragma unroll
    for (int i = 0; i < 4; ++i) {
        const float4 v0 = make_float4(acc[i][0], acc[i][1], acc[i][2], acc[i][3]);
        const float4 v1 = make_float4(acc[i][4], acc[i][5], acc[i][6], acc[i][7]);
        *reinterpret_cast<float4*>(Pb + (size_t)(b0 + i) * O + obase + o0) = v0;
        *reinterpret_cast<float4*>(Pb + (size_t)(b0 + i) * O + obase + o0 + 4) = v1;
    }
}

// ---------------------------------------------------------------------------
// u[b,h,:] = sum_k q[b,h,k]*Wk[h*64+k][:], q = sum 16 Pq + bq fused.
// grid (H, 8), block 256.
// ---------------------------------------------------------------------------
__global__ __launch_bounds__(256) void gemm_u(
    const float* __restrict__ Pq, const float* __restrict__ bq,
    const float* __restrict__ Wk, float* __restrict__ u)
{
    const int h = blockIdx.x;
    const int dbase = blockIdx.y * 128;
    const int tid = threadIdx.x;

    __shared__ float As[32][68];
    __shared__ float Ws[32][132];

    const int b0 = (tid >> 4) * 4;
    const int o0 = (tid & 15) * 8;

    float acc[4][8];
#pragma unroll
    for (int i = 0; i < 4; ++i)
#pragma unroll
        for (int j = 0; j < 8; ++j) acc[i][j] = 0.f;

    for (int kc = 0; kc < DH; kc += 32) {
#pragma unroll
        for (int j = 0; j < 2; ++j) {
            const int f = tid + 256 * j;
            const int bb = f >> 3, k4 = f & 7;
            const int kg = h * DH + kc + 4 * k4;
            float4 v = *reinterpret_cast<const float4*>(bq + kg);
#pragma unroll
            for (int s = 0; s < 16; ++s)
                v = f4add(v, *reinterpret_cast<const float4*>(
                    Pq + (size_t)(s * 64 + bb) * D + kg));
            As[4 * k4 + 0][bb] = v.x; As[4 * k4 + 1][bb] = v.y;
            As[4 * k4 + 2][bb] = v.z; As[4 * k4 + 3][bb] = v.w;
        }
#pragma unroll
        for (int j = 0; j < 4; ++j) {
            const int f = tid + 256 * j;
            const int k = f >> 5, d4 = f & 31;
            *reinterpret_cast<float4*>(&Ws[k][4 * d4]) =
                *reinterpret_cast<const float4*>(
                    Wk + (size_t)(h * DH + kc + k) * D + dbase + 4 * d4);
        }
        __syncthreads();
#pragma unroll 8
        for (int k = 0; k < 32; ++k) {
            const float4 av = *reinterpret_cast<const float4*>(&As[k][b0]);
            const float4 w0 = *reinterpret_cast<const float4*>(&Ws[k][o0]);
            const float4 w1 = *reinterpret_cast<const float4*>(&Ws[k][o0 + 4]);
            const float a[4] = {av.x, av.y, av.z, av.w};
            const float w[8] = {w0.x, w0.y, w0.z, w0.w, w1.x, w1.y, w1.z, w1.w};
#pragma unroll
            for (int i = 0; i < 4; ++i)
#pragma unroll
                for (int j = 0; j < 8; ++j)
                    acc[i][j] = fmaf(a[i], w[j], acc[i][j]);
        }
        __syncthreads();
    }
#pragma unroll
    for (int i = 0; i < 4; ++i) {
        const float4 v0 = make_float4(acc[i][0], acc[i][1], acc[i][2], acc[i][3]);
        const float4 v1 = make_float4(acc[i][4], acc[i][5], acc[i][6], acc[i][7]);
        float* ur = u + ((size_t)(b0 + i) * H + h) * D + dbase + o0;
        *reinterpret_cast<float4*>(ur) = v0;
        *reinterpret_cast<float4*>(ur + 4) = v1;
    }
}

// ---------------------------------------------------------------------------
// Streaming self-attn: grid (B,8), block 256. 8 groups of 32 lanes, each
// group computes TWO heads (halves LDS read amplification vs 1 head/group).
// Interleaved d-layout (seg*4): conflict-free LDS broadcast. Rows staged
// 2 at a time, double-buffered. exp without max-sub (|s|<~3, validated).
// ---------------------------------------------------------------------------
__global__ __launch_bounds__(256) void sattn_kernel(
    const float* __restrict__ cache_i, const float* __restrict__ x,
    const float* __restrict__ u, float* __restrict__ wp8,
    float* __restrict__ sums8)
{
    const int b = blockIdx.x, t8 = blockIdx.y;
    const int tid = threadIdx.x;
    const int hp = tid >> 5;
    const int h0 = hp * 2, h1 = h0 + 1;
    const int seg = tid & 31;
    const int dof = seg * 4;

    float4 u0[8], u1[8], a0[8], a1[8];
    const float* ub0 = u + ((size_t)(b * H + h0)) * D;
    const float* ub1 = u + ((size_t)(b * H + h1)) * D;
#pragma unroll
    for (int c = 0; c < 8; ++c) {
        float4 v = *reinterpret_cast<const float4*>(ub0 + c * 128 + dof);
        u0[c] = make_float4(v.x * SCALE, v.y * SCALE, v.z * SCALE, v.w * SCALE);
        v = *reinterpret_cast<const float4*>(ub1 + c * 128 + dof);
        u1[c] = make_float4(v.x * SCALE, v.y * SCALE, v.z * SCALE, v.w * SCALE);
        a0[c] = make_float4(0.f, 0.f, 0.f, 0.f);
        a1[c] = make_float4(0.f, 0.f, 0.f, 0.f);
    }
    float s0 = 0.f, s1 = 0.f;

    __shared__ float rowb[2][2][1024];
    const int tg0 = t8 * 64;
    const int lr = tid >> 7;            // staged row 0/1
    const int lcf = (tid & 127) * 8;    // 8 floats per thread

    auto rowptr = [&](int t) -> const float* {
        return (t < T) ? cache_i + ((size_t)t * B + b) * D : x + (size_t)b * D;
    };
    float4 pa = *reinterpret_cast<const float4*>(rowptr(tg0 + lr) + lcf);
    float4 pb = *reinterpret_cast<const float4*>(rowptr(tg0 + lr) + lcf + 4);

    for (int st = 0; st < 32; ++st) {
        const int p = st & 1;
        *reinterpret_cast<float4*>(&rowb[p][lr][lcf]) = pa;
        *reinterpret_cast<float4*>(&rowb[p][lr][lcf + 4]) = pb;
        __syncthreads();
        if (st + 1 < 32) {
            const int t = tg0 + 2 * (st + 1) + lr;
            pa = *reinterpret_cast<const float4*>(rowptr(t) + lcf);
            pb = *reinterpret_cast<const float4*>(rowptr(t) + lcf + 4);
        }
#pragma unroll
        for (int r = 0; r < 2; ++r) {
            const float* rowp = &rowb[p][r][0];
            float4 rv[8];
            float d0 = 0.f, d1 = 0.f;
#pragma unroll
            for (int c = 0; c < 8; ++c) {
                rv[c] = *reinterpret_cast<const float4*>(rowp + c * 128 + dof);
                d0 += dot4(u0[c], rv[c]);
                d1 += dot4(u1[c], rv[c]);
            }
#pragma unroll
            for (int m = 16; m >= 1; m >>= 1) {
                d0 += __shfl_xor(d0, m, 64);
                d1 += __shfl_xor(d1, m, 64);
            }
            const float e0 = __expf(d0), e1 = __expf(d1);
            s0 += e0; s1 += e1;
#pragma unroll
            for (int c = 0; c < 8; ++c) {
                a0[c].x = fmaf(e0, rv[c].x, a0[c].x);
                a0[c].y = fmaf(e0, rv[c].y, a0[c].y);
                a0[c].z = fmaf(e0, rv[c].z, a0[c].z);
                a0[c].w = fmaf(e0, rv[c].w, a0[c].w);
                a1[c].x = fmaf(e1, rv[c].x, a1[c].x);
                a1[c].y = fmaf(e1, rv[c].y, a1[c].y);
                a1[c].z = fmaf(e1, rv[c].z, a1[c].z);
                a1[c].w = fmaf(e1, rv[c].w, a1[c].w);
            }
        }
    }

    float* w0 = wp8 + ((size_t)((b * 8 + t8) * H + h0)) * D;
    float* w1 = wp8 + ((size_t)((b * 8 + t8) * H + h1)) * D;
#pragma unroll
    for (int c = 0; c < 8; ++c) {
        *reinterpret_cast<float4*>(w0 + c * 128 + dof) = a0[c];
        *reinterpret_cast<float4*>(w1 + c * 128 + dof) = a1[c];
    }
    if (seg == 0) {
        sums8[(b * 8 + t8) * H + h0] = s0;
        sums8[(b * 8 + t8) * H + h1] = s1;
    }
}

// ---------------------------------------------------------------------------
// ctx partial (k-slice of 128): A = (sum 8 wp8 partials)*(1/sumE).
// grid (H, 8), block 256.
// ---------------------------------------------------------------------------
__global__ __launch_bounds__(256) void gemm_ctx8(
    const float* __restrict__ wp8, const float* __restrict__ sums8,
    const float* __restrict__ Wv, float* __restrict__ P)
{
    const int h = blockIdx.x;
    const int kb = blockIdx.y * 128;
    const int tid = threadIdx.x;

    __shared__ float As[32][68];
    __shared__ float Ws[32][68];
    __shared__ float sinv[64];

    if (tid < 64) {
        float s = 0.f;
#pragma unroll
        for (int t = 0; t < 8; ++t) s += sums8[(tid * 8 + t) * H + h];
        sinv[tid] = 1.f / s;
    }
    __syncthreads();

    const int b0 = (tid >> 4) * 4;
    const int o0 = (tid & 15) * 4;

    float acc[4][4];
#pragma unroll
    for (int i = 0; i < 4; ++i)
#pragma unroll
        for (int j = 0; j < 4; ++j) acc[i][j] = 0.f;

    for (int kc = 0; kc < 128; kc += 32) {
#pragma unroll
        for (int j = 0; j < 2; ++j) {
            const int f = tid + 256 * j;
            const int bb = f >> 3, k4 = f & 7;
            const int kg = kb + kc + 4 * k4;
            float4 v = make_float4(0.f, 0.f, 0.f, 0.f);
#pragma unroll
            for (int t = 0; t < 8; ++t)
                v = f4add(v, *reinterpret_cast<const float4*>(
                    wp8 + ((size_t)((bb * 8 + t) * H + h)) * D + kg));
            const float iv = sinv[bb];
            As[4 * k4 + 0][bb] = v.x * iv; As[4 * k4 + 1][bb] = v.y * iv;
            As[4 * k4 + 2][bb] = v.z * iv; As[4 * k4 + 3][bb] = v.w * iv;
        }
#pragma unroll
        for (int j = 0; j < 2; ++j) {
            const int f = tid + 256 * j;
            const int oo = f >> 3, k4 = f & 7;
            const float4 v = *reinterpret_cast<const float4*>(
                Wv + (size_t)(h * DH + oo) * D + kb + kc + 4 * k4);
            Ws[4 * k4 + 0][oo] = v.x; Ws[4 * k4 + 1][oo] = v.y;
            Ws[4 * k4 + 2][oo] = v.z; Ws[4 * k4 + 3][oo] = v.w;
        }
        __syncthreads();
#pragma unroll 8
        for (int k = 0; k < 32; ++k) {
            const float4 av = *reinterpret_cast<const float4*>(&As[k][b0]);
            const float4 wv = *reinterpret_cast<const float4*>(&Ws[k][o0]);
            const float a[4] = {av.x, av.y, av.z, av.w};
            const float w[4] = {wv.x, wv.y, wv.z, wv.w};
#pragma unroll
            for (int i = 0; i < 4; ++i)
#pragma unroll
                for (int j = 0; j < 4; ++j)
                    acc[i][j] = fmaf(a[i], w[j], acc[i][j]);
        }
        __syncthreads();
    }
    float* Pb = P + (size_t)blockIdx.y * 64 * D;
#pragma unroll
    for (int i = 0; i < 4; ++i) {
        const float4 v = make_float4(acc[i][0], acc[i][1], acc[i][2], acc[i][3]);
        *reinterpret_cast<float4*>(Pb + (size_t)(b0 + i) * D + h * DH + o0) = v;
    }
}

// ---------------------------------------------------------------------------
// finish + residual + LayerNorm (O=D). grid B, block 256.
// ---------------------------------------------------------------------------
template <int KS>
__global__ __launch_bounds__(256) void finish_ln(
    const float* __restrict__ P, const float* __restrict__ bias,
    const float* __restrict__ resid, const float* __restrict__ g,
    const float* __restrict__ bb, float* __restrict__ out)
{
    const int b = blockIdx.x, tid = threadIdx.x;
    const float4* P4 = reinterpret_cast<const float4*>(P);
    float4 v = reinterpret_cast<const float4*>(bias)[tid];
    v = f4add(v, reinterpret_cast<const float4*>(resid + (size_t)b * D)[tid]);
#pragma unroll
    for (int s = 0; s < KS; ++s)
        v = f4add(v, P4[(size_t)(s * 64 + b) * 256 + tid]);

    float ssum = v.x + v.y + v.z + v.w;
#pragma unroll
    for (int m = 32; m >= 1; m >>= 1) ssum += __shfl_xor(ssum, m, 64);
    __shared__ float red[4];
    if ((tid & 63) == 0) red[tid >> 6] = ssum;
    __syncthreads();
    const float mean = (red[0] + red[1] + red[2] + red[3]) * (1.f / D);
    const float dx = v.x - mean, dy = v.y - mean, dz = v.z - mean, dw = v.w - mean;
    float q = dx * dx + dy * dy + dz * dz + dw * dw;
#pragma unroll
    for (int m = 32; m >= 1; m >>= 1) q += __shfl_xor(q, m, 64);
    __shared__ float red2[4];
    if ((tid & 63) == 0) red2[tid >> 6] = q;
    __syncthreads();
    const float var = (red2[0] + red2[1] + red2[2] + red2[3]) * (1.f / D);
    const float rs = rsqrtf(var + EPS);
    const float4 gv = reinterpret_cast<const float4*>(g)[tid];
    const float4 bv = reinterpret_cast<const float4*>(bb)[tid];
    float4 o;
    o.x = dx * rs * gv.x + bv.x;
    o.y = dy * rs * gv.y + bv.y;
    o.z = dz * rs * gv.z + bv.z;
    o.w = dw * rs * gv.w + bv.w;
    reinterpret_cast<float4*>(out + (size_t)b * D)[tid] = o;
}

// ---------------------------------------------------------------------------
// Fused attention for one (b,h). q (and HASX extra k/v row) built in LDS
// from NPART split-K partials (pitch QP) + bias. grid (B,H), block 256.
// ---------------------------------------------------------------------------
template <int NS, bool HASX, int NPART, int QP>
__global__ __launch_bounds__(256) void attn_kernel(
    const float* __restrict__ qP, const float* __restrict__ qbias,
    const float* __restrict__ Kb, const float* __restrict__ Vb,
    float* __restrict__ ctx, int nk)
{
    const int b = blockIdx.x, h = blockIdx.y, tid = threadIdx.x;
    __shared__ float qs[DH], kx[DH], vx[DH];
    __shared__ float sa[NS];
    __shared__ float red[1088];
    __shared__ float r1[4], r2[4];

    {
        const int grp = tid >> 6, col = tid & 63;
        constexpr int NP4 = NPART / 4;
        const int colg = h * DH + col;
        float aq = 0.f, ak = 0.f, av = 0.f;
#pragma unroll
        for (int s = 0; s < NP4; ++s) {
            const float* base = qP + (size_t)((grp * NP4 + s) * 64 + b) * QP + colg;
            aq += base[0];
            if (HASX) { ak += base[D]; av += base[2 * D]; }
        }
        red[grp * 64 + col] = aq;
        if (HASX) {
            red[256 + grp * 64 + col] = ak;
            red[512 + grp * 64 + col] = av;
        }
        __syncthreads();
        if (tid < 64) {
            qs[tid] = qbias[h * DH + tid] + red[tid] + red[64 + tid] +
                      red[128 + tid] + red[192 + tid];
            if (HASX) {
                kx[tid] = qbias[D + h * DH + tid] + red[256 + tid] +
                          red[320 + tid] + red[384 + tid] + red[448 + tid];
                vx[tid] = qbias[2 * D + h * DH + tid] + red[512 + tid] +
                          red[576 + tid] + red[640 + tid] + red[704 + tid];
            }
        }
        __syncthreads();
    }

    const int ss = tid >> 2, pp = tid & 3;
    const float* Kbh = Kb + ((size_t)(b * H + h)) * nk * DH;
#pragma unroll 2
    for (int pass = 0; pass < NS / 64; ++pass) {
        const int s = pass * 64 + ss;
        const float* row = (!HASX || s < nk) ? (Kbh + (size_t)s * DH)
                                             : (const float*)kx;
        const float4* rp = reinterpret_cast<const float4*>(row);
        const float4* qp = reinterpret_cast<const float4*>(qs);
        float acc = 0.f;
#pragma unroll
        for (int c = 0; c < 4; ++c) acc += dot4(rp[pp * 4 + c], qp[pp * 4 + c]);
        acc += __shfl_xor(acc, 1, 64);
        acc += __shfl_xor(acc, 2, 64);
        if (pp == 0) sa[s] = acc * SCALE;
    }
    __syncthreads();

    float m = -1e30f;
    for (int k = tid; k < NS; k += 256) m = fmaxf(m, sa[k]);
#pragma unroll
    for (int mm = 32; mm >= 1; mm >>= 1) m = fmaxf(m, __shfl_xor(m, mm, 64));
    if ((tid & 63) == 0) r1[tid >> 6] = m;
    __syncthreads();
    m = fmaxf(fmaxf(r1[0], r1[1]), fmaxf(r1[2], r1[3]));
    float sum = 0.f;
    for (int k = tid; k < NS; k += 256) {
        const float e = __expf(sa[k] - m);
        sa[k] = e;
        sum += e;
    }
#pragma unroll
    for (int mm = 32; mm >= 1; mm >>= 1) sum += __shfl_xor(sum, mm, 64);
    if ((tid & 63) == 0) r2[tid >> 6] = sum;
    __syncthreads();
    const float inv = 1.f / (r2[0] + r2[1] + r2[2] + r2[3]);

    const int dh4 = tid & 15, sq = tid >> 4;
    const float* Vbh = Vb + ((size_t)(b * H + h)) * nk * DH;
    float4 acc = make_float4(0.f, 0.f, 0.f, 0.f);
#pragma unroll 2
    for (int s = sq; s < NS; s += 16) {
        const float* row = (!HASX || s < nk) ? (Vbh + (size_t)s * DH)
                                             : (const float*)vx;
        const float4 vv = *reinterpret_cast<const float4*>(row + dh4 * 4);
        const float aw = sa[s];
        acc.x += aw * vv.x; acc.y += aw * vv.y;
        acc.z += aw * vv.z; acc.w += aw * vv.w;
    }
    __syncthreads();
    *reinterpret_cast<float4*>(&red[sq * 68 + dh4 * 4]) = acc;
    __syncthreads();
    if (tid < 64) {
        float t = 0.f;
#pragma unroll
        for (int k = 0; k < 16; ++k) t += red[k * 68 + tid];
        ctx[(size_t)b * D + h * DH + tid] = t * inv;
    }
}

// ---------------------------------------------------------------------------
extern "C" void kernel_launch(void* const* d_in, const int* in_sizes, int n_in,
                              void* d_out, int out_size, void* d_ws, size_t ws_size,
                              hipStream_t stream)
{
    const float* tgt_last = (const float*)d_in[0];
    const float* cache    = (const float*)d_in[1];
    const float* K0       = (const float*)d_in[2];
    const float* V0       = (const float*)d_in[3];
    const float* K_mem    = (const float*)d_in[4];
    const float* V_mem    = (const float*)d_in[5];
    const float* sa_W     = (const float*)d_in[6];
    const float* sa_b     = (const float*)d_in[7];
    const float* sa_oW    = (const float*)d_in[8];
    const float* sa_ob    = (const float*)d_in[9];
    const float* ca_qW    = (const float*)d_in[10];
    const float* ca_qb    = (const float*)d_in[11];
    const float* ca_oW    = (const float*)d_in[12];
    const float* ca_ob    = (const float*)d_in[13];
    const float* W1       = (const float*)d_in[14];
    const float* b1       = (const float*)d_in[15];
    const float* W2       = (const float*)d_in[16];
    const float* b2       = (const float*)d_in[17];
    const float* ln1_g    = (const float*)d_in[18];
    const float* ln1_b    = (const float*)d_in[19];
    const float* ln2_g    = (const float*)d_in[20];
    const float* ln2_b    = (const float*)d_in[21];
    const float* ln3_g    = (const float*)d_in[22];
    const float* ln3_b    = (const float*)d_in[23];

    float* ws = (float*)d_ws;
    float* x_buf  = ws;                  // 65,536
    float* ctx_b  = ws + 65536;          // 65,536
    float* u_buf  = ws + 131072;         // 1,048,576
    float* wp8    = ws + 1179648;        // 8,388,608  (512*16*1024)
    float* sums8  = ws + 9568256;        // 8,192
    float* Pq     = ws + 9576448;        // 16*B*D = 1,048,576
    float* Pqkv   = ws + 10625024;       // 16*B*3D = 3,145,728
    float* Pc     = ws + 13770752;       // 8*B*D = 524,288
    float* PA     = ws + 14295040;       // 32*B*D = 2,097,152
    float* Pf1    = ws + 16392192;       // 16*B*DFF = 4,194,304
    float* Pf2    = ws + 20586496;       // 64*B*D = 4,194,304

    const dim3 blk(256);

    for (int i = 0; i < NLAYER; ++i) {
        const float* Wqkv = sa_W + (size_t)i * 3 * D * D;
        const float* bqkv = sa_b + (size_t)i * 3 * D;
        const float* xin = (i == 0) ? tgt_last : x_buf;

        if (i == 0) {
            gemm_proj<D, 16><<<dim3(24, 16), blk, 0, stream>>>(tgt_last, Wqkv, Pqkv);
            attn_kernel<TT, true, 16, 3 * D><<<dim3(B, H), blk, 0, stream>>>(
                Pqkv, bqkv, K0, V0, ctx_b, T);
        } else {
            const float* cache_i = cache + (size_t)i * T * B * D;
            gemm_proj<D, 16><<<dim3(8, 16), blk, 0, stream>>>(x_buf, Wqkv, Pq);
            gemm_u<<<dim3(H, 8), blk, 0, stream>>>(
                Pq, bqkv, Wqkv + (size_t)D * D, u_buf);
            sattn_kernel<<<dim3(B, 8), blk, 0, stream>>>(
                cache_i, x_buf, u_buf, wp8, sums8);
            gemm_ctx8<<<dim3(H, 8), blk, 0, stream>>>(
                wp8, sums8, Wqkv + (size_t)2 * D * D, Pc);
        }

        // self-attn output projection (+v-bias into A) + LN1
        if (i == 0) {
            gemm_proj<D, 32><<<dim3(8, 32), blk, 0, stream>>>(
                ctx_b, sa_oW + (size_t)i * D * D, PA);
        } else {
            gemm_psum<D, 32, 8, false><<<dim3(8, 32), blk, 0, stream>>>(
                Pc, bqkv + 2 * D, sa_oW + (size_t)i * D * D, PA);
        }
        finish_ln<32><<<dim3(B), blk, 0, stream>>>(
            PA, sa_ob + (size_t)i * D, xin,
            ln1_g + (size_t)i * D, ln1_b + (size_t)i * D, x_buf);

        // cross attention
        gemm_proj<D, 32><<<dim3(8, 32), blk, 0, stream>>>(
            x_buf, ca_qW + (size_t)i * D * D, PA);
        attn_kernel<SMEM, false, 32, D><<<dim3(B, H), blk, 0, stream>>>(
            PA, ca_qb + (size_t)i * D,
            K_mem + (size_t)i * B * H * SMEM * DH,
            V_mem + (size_t)i * B * H * SMEM * DH, ctx_b, SMEM);
        gemm_proj<D, 32><<<dim3(8, 32), blk, 0, stream>>>(
            ctx_b, ca_oW + (size_t)i * D * D, PA);
        finish_ln<32><<<dim3(B), blk, 0, stream>>>(
            PA, ca_ob + (size_t)i * D, x_buf,
            ln2_g + (size_t)i * D, ln2_b + (size_t)i * D, x_buf);

        // FFN
        gemm_proj<D, 16><<<dim3(32, 16), blk, 0, stream>>>(
            x_buf, W1 + (size_t)i * DFF * D, Pf1);
        gemm_psum<DFF, 64, 16, true><<<dim3(8, 64), blk, 0, stream>>>(
            Pf1, b1 + (size_t)i * DFF, W2 + (size_t)i * D * DFF, Pf2);
        float* lnout = (i == NLAYER - 1) ? (float*)d_out : x_buf;
        finish_ln<64><<<dim3(B), blk, 0, stream>>>(
            Pf2, b2 + (size_t)i * D, x_buf,
            ln3_g + (size_t)i * D, ln3_b + (size_t)i * D, lnout);
    }
}